// Round 12
// baseline (170.249 us; speedup 1.0000x reference)
//
#include <hip/hip_runtime.h>
#include <hip/hip_bf16.h>

// Round 12 (5th submit; r8-r11 benches were GPUAcquisitionTimeouts).
// = split-K occupancy test with RACE-FREE two-kernel combine.
// r11 post-mortem: single-kernel flag combine returned plausible-but-wrong
// values = combiner read stale/zero partials -> cross-XCD visibility of
// non-atomic stores under __threadfence not trustworthy. Fix: kernel
// boundary IS the fence (HSA dispatch edges = device-scope release/acquire,
// L2 writeback+invalidate). Stream-ordered second kernel does the combine.
//   k1 fattn_split: grid (32,16,2)=1024 blocks x 8 waves = 8 waves/SIMD
//      issued, 4 blocks/CU resident (36KB LDS, VGPR<=64 via fused softmax).
//      Each block: half the keys (16 tiles), writes unnormalized (O,l).
//   k2 fattn_combine: O=(O0+O1)/(l0+l1), 512 blocks, ~50MB -> ~10us.
// Fixed-base softmax => partials combine linearly (no max bookkeeping).
// Block structure otherwise = r9 (verified: 0 bank conflicts, 1 barrier/
// tile, conflict-free subtiled LDS, reg prefetch, mask in QK C-init).
// Fallback: verbatim r9 kernel if ws_size too small.

typedef __attribute__((ext_vector_type(8))) short bf16x8;
typedef __attribute__((ext_vector_type(4))) short bf16x4;
typedef __attribute__((ext_vector_type(4))) float f32x4;

#define B_ 2
#define S_ 2048
#define H_ 16
#define D_ 64
#define BQ 128
#define BK 64
#define QT_ (S_ / BQ)          // 16 q-tiles
#define NSP 2                  // key-split factor
#define NT (S_ / BK)           // 32 key tiles total
#define NTH (NT / NSP)         // 16 per split block
#define ROWSZ (H_ * D_)        // 1024 floats between s rows
#define NREG (B_ * H_ * QT_ * NSP)   // 1024 partial regions
#define REGSZ (512 * 16)             // floats per O-partial region

#define LOG2E  1.44269504088896340736f
#define SCALE2 (0.125f * LOG2E)

__device__ __forceinline__ unsigned pack2(float a, float b) {
    union { __hip_bfloat162 h; unsigned u; } x;
    x.h = __float22bfloat162_rn(make_float2(a, b));   // v_cvt_pk_bf16_f32
    return x.u;
}

__device__ __forceinline__ float fexp2(float x) {
#if __has_builtin(__builtin_amdgcn_exp2f)
    return __builtin_amdgcn_exp2f(x);
#else
    return __expf(x * 0.69314718055994531f);
#endif
}

__device__ __forceinline__ f32x4 mfma16(bf16x4 a, bf16x4 b, f32x4 c) {
#if __has_builtin(__builtin_amdgcn_mfma_f32_16x16x16bf16_1k)
    return __builtin_amdgcn_mfma_f32_16x16x16bf16_1k(a, b, c, 0, 0, 0);
#else
    bf16x8 a8 = {a[0], a[1], a[2], a[3], 0, 0, 0, 0};
    bf16x8 b8 = {b[0], b[1], b[2], b[3], 0, 0, 0, 0};
    return __builtin_amdgcn_mfma_f32_16x16x32_bf16(a8, b8, c, 0, 0, 0);
#endif
}

// ---------------------------------------------------------------- split-K
__global__ __launch_bounds__(512, 8)
void fattn_split(const float* __restrict__ qg,
                 const float* __restrict__ kg,
                 const float* __restrict__ vg,
                 const float* __restrict__ maskg,
                 float* __restrict__ wso,      // [NREG][REGSZ]
                 float* __restrict__ wsl)      // [NREG][512]
{
    __shared__ __attribute__((aligned(16))) ushort Ks[2][4096];
    __shared__ __attribute__((aligned(16))) ushort Vt[2][4096];
    __shared__ __attribute__((aligned(16))) float  Em[S_ / NSP];

    const int qt = blockIdx.x & 15, sp = blockIdx.x >> 4;
    const int h = blockIdx.y, b = blockIdx.z;
    const int tid = threadIdx.x;
    const int w = tid >> 6, lane = tid & 63, g = lane >> 4, l15 = lane & 15;

    // ---- stage this half's pre-scaled mask (1024 floats, 256 threads) ----
    if (tid < 256) {
        float4 mv = *(const float4*)(maskg + (size_t)b * S_
                                     + sp * (S_ / NSP) + tid * 4);
        *(float4*)&Em[tid * 4] = make_float4(mv.x * LOG2E, mv.y * LOG2E,
                                             mv.z * LOG2E, mv.w * LOG2E);
    }

    // ---- Q fragment (B-operand, x32), scale folded in ----
    const int qrow = qt * BQ + w * 16 + l15;
    const float* qp = qg + (size_t)(b * S_ + qrow) * ROWSZ + h * D_;
    bf16x8 qf[2];
#pragma unroll
    for (int half = 0; half < 2; ++half) {
        float4 f0 = *(const float4*)(qp + half * 32 + g * 8);
        float4 f1 = *(const float4*)(qp + half * 32 + g * 8 + 4);
        union { bf16x8 v; uint4 u; } x;
        x.u = make_uint4(pack2(f0.x * SCALE2, f0.y * SCALE2),
                         pack2(f0.z * SCALE2, f0.w * SCALE2),
                         pack2(f1.x * SCALE2, f1.y * SCALE2),
                         pack2(f1.z * SCALE2, f1.w * SCALE2));
        qf[half] = x.v;
    }

    // ---- staging maps (conflict-free layouts, verified r9) ----
    const int skey = tid >> 4;
    const int sd   = (tid & 15) * 4;
    const int kw0 = (skey >> 4) * 1024
                  + ((sd >> 3) + ((skey >> 3) & 1) * 8) * 64
                  + (((skey & 7) ^ (sd >> 3)) << 3) + (sd & 7);
    const int kw1 = kw0 + 2048;
    const int vwA = ((w >> 1) * 4 + (lane >> 4)) * 256
                  + ((2 * w) & 3) * 64 + (lane & 15) * 4;
    const int vwB = vwA + 64;

    const size_t kvbase = (size_t)b * S_ * ROWSZ + h * D_
                        + (size_t)sp * (S_ / NSP) * ROWSZ;
    const float* kgs = kg + kvbase;
    const float* vgs = vg + kvbase;

    float4 kpre0, kpre1;
    float  vpre[8];
    auto prefetch = [&](int ktl) {
        const float* kb = kgs + (size_t)ktl * BK * ROWSZ;
        kpre0 = *(const float4*)(kb + (size_t)skey * ROWSZ + sd);
        kpre1 = *(const float4*)(kb + (size_t)(skey + 32) * ROWSZ + sd);
        const float* vb = vgs + (size_t)ktl * BK * ROWSZ + lane;
#pragma unroll
        for (int i = 0; i < 8; ++i) vpre[i] = vb[(size_t)(w * 8 + i) * ROWSZ];
    };
    auto stage = [&](int buf) {
        *(uint2*)&Ks[buf][kw0] =
            make_uint2(pack2(kpre0.x, kpre0.y), pack2(kpre0.z, kpre0.w));
        *(uint2*)&Ks[buf][kw1] =
            make_uint2(pack2(kpre1.x, kpre1.y), pack2(kpre1.z, kpre1.w));
        *(uint2*)&Vt[buf][vwA] =
            make_uint2(pack2(vpre[0], vpre[1]), pack2(vpre[2], vpre[3]));
        *(uint2*)&Vt[buf][vwB] =
            make_uint2(pack2(vpre[4], vpre[5]), pack2(vpre[6], vpre[7]));
    };

    float l_r = 0.0f;
    f32x4 o_acc[4];
#pragma unroll
    for (int t = 0; t < 4; ++t) o_acc[t] = (f32x4){0.f, 0.f, 0.f, 0.f};

    prefetch(0);
    stage(0);
    __syncthreads();

    const int krd0 = (g + (l15 >> 3) * 8) * 64 + (((l15 & 7) ^ g) << 3);
    const int krd1 = (g + 4 + (l15 >> 3) * 8) * 64 + (((l15 & 7) ^ (g + 4)) << 3);
    const int vrd = g * 64 + l15 * 4;

    for (int ktl = 0; ktl < NTH; ++ktl) {
        const int cur = ktl & 1;
        if (ktl + 1 < NTH) prefetch(ktl + 1);

        // ---- QK + fused softmax (VGPR diet: no sv[4][4]) ----
        const ushort* ks = Ks[cur];
        bf16x4 pf[4];
        float rs = 0.f;
#pragma unroll
        for (int t = 0; t < 4; ++t) {
            f32x4 acc = *(const f32x4*)&Em[ktl * BK + t * 16 + g * 4];
            bf16x8 kf0 = *(const bf16x8*)&ks[t * 1024 + krd0];
            bf16x8 kf1 = *(const bf16x8*)&ks[t * 1024 + krd1];
            acc = __builtin_amdgcn_mfma_f32_16x16x32_bf16(kf0, qf[0], acc, 0, 0, 0);
            acc = __builtin_amdgcn_mfma_f32_16x16x32_bf16(kf1, qf[1], acc, 0, 0, 0);
            float p0 = fexp2(acc[0]), p1 = fexp2(acc[1]);
            float p2 = fexp2(acc[2]), p3 = fexp2(acc[3]);
            rs += (p0 + p1) + (p2 + p3);
            union { bf16x4 v; uint2 u; } x;
            x.u = make_uint2(pack2(p0, p1), pack2(p2, p3));
            pf[t] = x.v;
        }
        l_r += rs;

        // ---- O^T += V^T P^T : conflict-free b64 reads, 4 acc chains ----
        const ushort* vt = Vt[cur];
#pragma unroll
        for (int c = 0; c < 4; ++c)
#pragma unroll
            for (int t2 = 0; t2 < 4; ++t2) {
                bf16x4 vf = *(const bf16x4*)&vt[(c * 4 + t2) * 256 + vrd];
                o_acc[t2] = mfma16(vf, pf[c], o_acc[t2]);
            }

        if (ktl + 1 < NTH) stage(cur ^ 1);
        __syncthreads();
    }

    // ---- reduce l across quads; write unnormalized partial (coalesced) ----
    l_r += __shfl_xor(l_r, 16);
    l_r += __shfl_xor(l_r, 32);

    const int region = ((b * H_ + h) * QT_ + qt) * NSP + sp;
    float* po = wso + (size_t)region * REGSZ + tid * 16;
#pragma unroll
    for (int t2 = 0; t2 < 4; ++t2) *(f32x4*)(po + t2 * 4) = o_acc[t2];
    wsl[(size_t)region * 512 + tid] = l_r;
}

// ---------------------------------------------------- combine (kernel 2)
__global__ __launch_bounds__(512, 8)
void fattn_combine(const float* __restrict__ wso,
                   const float* __restrict__ wsl,
                   float* __restrict__ outg)
{
    const int qt = blockIdx.x, h = blockIdx.y, b = blockIdx.z;
    const int tid = threadIdx.x;
    const int w = tid >> 6, lane = tid & 63, g = lane >> 4, l15 = lane & 15;

    const int bhq = (b * H_ + h) * QT_ + qt;
    const float* p0 = wso + (size_t)(bhq * NSP + 0) * REGSZ + tid * 16;
    const float* p1 = wso + (size_t)(bhq * NSP + 1) * REGSZ + tid * 16;
    const float  l  = wsl[(size_t)(bhq * NSP + 0) * 512 + tid]
                    + wsl[(size_t)(bhq * NSP + 1) * 512 + tid];
    const float inv = 1.0f / l;

    const int qrow = qt * BQ + w * 16 + l15;
    float* op = outg + (size_t)(b * S_ + qrow) * ROWSZ + h * D_;
#pragma unroll
    for (int t2 = 0; t2 < 4; ++t2) {
        f32x4 a = *(const f32x4*)(p0 + t2 * 4);
        f32x4 c = *(const f32x4*)(p1 + t2 * 4);
#pragma unroll
        for (int r = 0; r < 4; ++r)
            op[t2 * 16 + g * 4 + r] = (a[r] + c[r]) * inv;
    }
}

// ------------------------------------------------- fallback: verbatim r9
__global__ __launch_bounds__(512, 4)
void fattn_kernel(const float* __restrict__ qg,
                  const float* __restrict__ kg,
                  const float* __restrict__ vg,
                  const float* __restrict__ maskg,
                  float* __restrict__ outg)
{
    __shared__ __attribute__((aligned(16))) ushort Ks[2][4096];
    __shared__ __attribute__((aligned(16))) ushort Vt[2][4096];
    __shared__ __attribute__((aligned(16))) float  Em[S_];

    const int qt = blockIdx.x, h = blockIdx.y, b = blockIdx.z;
    const int tid = threadIdx.x;
    const int w = tid >> 6, lane = tid & 63, g = lane >> 4, l15 = lane & 15;

    {
        float4 mv = *(const float4*)(maskg + (size_t)b * S_ + tid * 4);
        *(float4*)&Em[tid * 4] = make_float4(mv.x * LOG2E, mv.y * LOG2E,
                                             mv.z * LOG2E, mv.w * LOG2E);
    }

    const int qrow = qt * BQ + w * 16 + l15;
    const float* qp = qg + (size_t)(b * S_ + qrow) * ROWSZ + h * D_;
    bf16x8 qf[2];
#pragma unroll
    for (int half = 0; half < 2; ++half) {
        float4 f0 = *(const float4*)(qp + half * 32 + g * 8);
        float4 f1 = *(const float4*)(qp + half * 32 + g * 8 + 4);
        union { bf16x8 v; uint4 u; } x;
        x.u = make_uint4(pack2(f0.x * SCALE2, f0.y * SCALE2),
                         pack2(f0.z * SCALE2, f0.w * SCALE2),
                         pack2(f1.x * SCALE2, f1.y * SCALE2),
                         pack2(f1.z * SCALE2, f1.w * SCALE2));
        qf[half] = x.v;
    }

    const int skey = tid >> 4;
    const int sd   = (tid & 15) * 4;
    const int kw0 = (skey >> 4) * 1024
                  + ((sd >> 3) + ((skey >> 3) & 1) * 8) * 64
                  + (((skey & 7) ^ (sd >> 3)) << 3) + (sd & 7);
    const int kw1 = kw0 + 2048;
    const int vwA = ((w >> 1) * 4 + (lane >> 4)) * 256
                  + ((2 * w) & 3) * 64 + (lane & 15) * 4;
    const int vwB = vwA + 64;

    const size_t kvbase = (size_t)b * S_ * ROWSZ + h * D_;

    float4 kpre0, kpre1;
    float  vpre[8];
    auto prefetch = [&](int kt) {
        const float* kb = kg + kvbase + (size_t)kt * BK * ROWSZ;
        kpre0 = *(const float4*)(kb + (size_t)skey * ROWSZ + sd);
        kpre1 = *(const float4*)(kb + (size_t)(skey + 32) * ROWSZ + sd);
        const float* vb = vg + kvbase + (size_t)kt * BK * ROWSZ + lane;
#pragma unroll
        for (int i = 0; i < 8; ++i) vpre[i] = vb[(size_t)(w * 8 + i) * ROWSZ];
    };
    auto stage = [&](int buf) {
        *(uint2*)&Ks[buf][kw0] =
            make_uint2(pack2(kpre0.x, kpre0.y), pack2(kpre0.z, kpre0.w));
        *(uint2*)&Ks[buf][kw1] =
            make_uint2(pack2(kpre1.x, kpre1.y), pack2(kpre1.z, kpre1.w));
        *(uint2*)&Vt[buf][vwA] =
            make_uint2(pack2(vpre[0], vpre[1]), pack2(vpre[2], vpre[3]));
        *(uint2*)&Vt[buf][vwB] =
            make_uint2(pack2(vpre[4], vpre[5]), pack2(vpre[6], vpre[7]));
    };

    float l_r = 0.0f;
    f32x4 o_acc[4];
#pragma unroll
    for (int t = 0; t < 4; ++t) o_acc[t] = (f32x4){0.f, 0.f, 0.f, 0.f};

    prefetch(0);
    stage(0);
    __syncthreads();

    const int krd0 = (g + (l15 >> 3) * 8) * 64 + (((l15 & 7) ^ g) << 3);
    const int krd1 = (g + 4 + (l15 >> 3) * 8) * 64 + (((l15 & 7) ^ (g + 4)) << 3);
    const int vrd = g * 64 + l15 * 4;

    for (int kt = 0; kt < NT; ++kt) {
        const int cur = kt & 1;
        if (kt + 1 < NT) prefetch(kt + 1);

        const ushort* ks = Ks[cur];
        float sv[4][4];
#pragma unroll
        for (int t = 0; t < 4; ++t) {
            f32x4 acc = *(const f32x4*)&Em[kt * BK + t * 16 + g * 4];
            bf16x8 kf0 = *(const bf16x8*)&ks[t * 1024 + krd0];
            bf16x8 kf1 = *(const bf16x8*)&ks[t * 1024 + krd1];
            acc = __builtin_amdgcn_mfma_f32_16x16x32_bf16(kf0, qf[0], acc, 0, 0, 0);
            acc = __builtin_amdgcn_mfma_f32_16x16x32_bf16(kf1, qf[1], acc, 0, 0, 0);
            sv[t][0] = acc[0]; sv[t][1] = acc[1]; sv[t][2] = acc[2]; sv[t][3] = acc[3];
        }

        float rs = 0.f;
#pragma unroll
        for (int t = 0; t < 4; ++t)
#pragma unroll
            for (int r = 0; r < 4; ++r) {
                float p = fexp2(sv[t][r]);
                sv[t][r] = p;
                rs += p;
            }
        l_r += rs;

        bf16x4 pf[4];
#pragma unroll
        for (int c = 0; c < 4; ++c) {
            union { bf16x4 v; uint2 u; } x;
            x.u = make_uint2(pack2(sv[c][0], sv[c][1]), pack2(sv[c][2], sv[c][3]));
            pf[c] = x.v;
        }

        const ushort* vt = Vt[cur];
#pragma unroll
        for (int c = 0; c < 4; ++c)
#pragma unroll
            for (int t2 = 0; t2 < 4; ++t2) {
                bf16x4 vf = *(const bf16x4*)&vt[(c * 4 + t2) * 256 + vrd];
                o_acc[t2] = mfma16(vf, pf[c], o_acc[t2]);
            }

        if (kt + 1 < NT) stage(cur ^ 1);
        __syncthreads();
    }

    l_r += __shfl_xor(l_r, 16);
    l_r += __shfl_xor(l_r, 32);
    const float inv = 1.0f / l_r;
    float* op = outg + (size_t)(b * S_ + qrow) * ROWSZ + h * D_;
#pragma unroll
    for (int t2 = 0; t2 < 4; ++t2)
#pragma unroll
        for (int r = 0; r < 4; ++r)
            op[t2 * 16 + g * 4 + r] = o_acc[t2][r] * inv;
}

extern "C" void kernel_launch(void* const* d_in, const int* in_sizes, int n_in,
                              void* d_out, int out_size, void* d_ws, size_t ws_size,
                              hipStream_t stream) {
    const size_t O_BYTES = (size_t)NREG * REGSZ * 4;            // 32 MiB
    const size_t L_BYTES = (size_t)NREG * 512 * 4;              // 2 MiB
    const size_t NEED = O_BYTES + L_BYTES;
    if (d_ws != nullptr && ws_size >= NEED) {
        float* wso = (float*)d_ws;
        float* wsl = (float*)((char*)d_ws + O_BYTES);
        dim3 grid1(QT_ * NSP, H_, B_);   // (32,16,2) = 1024 blocks
        fattn_split<<<grid1, dim3(512), 0, stream>>>(
            (const float*)d_in[0], (const float*)d_in[1], (const float*)d_in[2],
            (const float*)d_in[3], wso, wsl);
        dim3 grid2(QT_, H_, B_);         // (16,16,2) = 512 blocks
        fattn_combine<<<grid2, dim3(512), 0, stream>>>(wso, wsl, (float*)d_out);
    } else {
        dim3 grid(QT_, H_, B_);          // fallback: r9 exact
        fattn_kernel<<<grid, dim3(512), 0, stream>>>(
            (const float*)d_in[0], (const float*)d_in[1], (const float*)d_in[2],
            (const float*)d_in[3], (float*)d_out);
    }
}

// Round 14
// 145.622 us; speedup vs baseline: 1.1691x; 1.1691x over previous
//
#include <hip/hip_runtime.h>
#include <hip/hip_bf16.h>

// Round 13 (resubmit; prior bench was a GPUAcquisitionTimeout, never ran).
// = r9 shell + intra-block key-split ACROSS WAVES to halve LDS reads.
// History: r9 (72us, conflicts 0) is latency-limited by NO saturated pipe;
// r10/r12 proved 2x occupancy does NOT help (MFMA/VALU busy-time constant,
// dur worse) -> occupancy exonerated. Remaining suspect: per-CU LDS pipe at
// ~65% (est. 224 cyc/wave-tile: 8 b128 + 16 b64 reads + writes) -> queueing
// stalls on every wave. Fix: wave w = (wq=w&3, wk=w>>2) computes 32 q-rows x
// 32 keys per tile (vs 16q x 64k): K reads 8->4 b128, V reads 16->8 b64
// (each read feeds 2 MFMA via q-reuse); exp2/MFMA/staging per wave-tile
// unchanged; LDS ~124 cyc/wave-tile (-45%). Partner waves (wk 0/1) combine
// linear fixed-base partials O=(O0+O1)/(l0+l1) intra-block via LDS overlay
// at the end (one-shot epilogue; r10's combine was numerically correct).
// Everything else identical to r9: 512 blocks x 8 waves (2 blk/CU), same
// conflict-free subtiled layouts + staging maps, reg prefetch, 1 barrier/
// tile, mask in QK C-init, scale folded into Q, fixed-base softmax.

typedef __attribute__((ext_vector_type(8))) short bf16x8;
typedef __attribute__((ext_vector_type(4))) short bf16x4;
typedef __attribute__((ext_vector_type(4))) float f32x4;

#define B_ 2
#define S_ 2048
#define H_ 16
#define D_ 64
#define BQ 128
#define BK 64
#define NT (S_ / BK)
#define ROWSZ (H_ * D_)        // 1024 floats between s rows

#define LOG2E  1.44269504088896340736f
#define SCALE2 (0.125f * LOG2E)

__device__ __forceinline__ unsigned pack2(float a, float b) {
    union { __hip_bfloat162 h; unsigned u; } x;
    x.h = __float22bfloat162_rn(make_float2(a, b));   // v_cvt_pk_bf16_f32
    return x.u;
}

__device__ __forceinline__ float fexp2(float x) {
#if __has_builtin(__builtin_amdgcn_exp2f)
    return __builtin_amdgcn_exp2f(x);
#else
    return __expf(x * 0.69314718055994531f);
#endif
}

__device__ __forceinline__ f32x4 mfma16(bf16x4 a, bf16x4 b, f32x4 c) {
#if __has_builtin(__builtin_amdgcn_mfma_f32_16x16x16bf16_1k)
    return __builtin_amdgcn_mfma_f32_16x16x16bf16_1k(a, b, c, 0, 0, 0);
#else
    bf16x8 a8 = {a[0], a[1], a[2], a[3], 0, 0, 0, 0};
    bf16x8 b8 = {b[0], b[1], b[2], b[3], 0, 0, 0, 0};
    return __builtin_amdgcn_mfma_f32_16x16x32_bf16(a8, b8, c, 0, 0, 0);
#endif
}

__global__ __launch_bounds__(512, 4)
void fattn_kernel(const float* __restrict__ qg,
                  const float* __restrict__ kg,
                  const float* __restrict__ vg,
                  const float* __restrict__ maskg,
                  float* __restrict__ outg)
{
    // Pool: K bufs [0,8192), V bufs [8192,16384) ushorts; epilogue overlay
    // reuses the full 32KB as f32x4[8][256] for O partials.
    __shared__ __attribute__((aligned(16))) ushort Pool[16384];
    __shared__ __attribute__((aligned(16))) float  Em[S_];   // mask * log2e

    ushort* Ks = Pool;            // [2][4096]
    ushort* Vt = Pool + 8192;     // [2][4096]

    const int qt = blockIdx.x, h = blockIdx.y, b = blockIdx.z;
    const int tid = threadIdx.x;
    const int w = tid >> 6, lane = tid & 63, g = lane >> 4, l15 = lane & 15;
    const int wq = w & 3, wk = w >> 2;   // q-group, key-half

    // ---- stage pre-scaled mask to LDS (once) ----
    {
        float4 mv = *(const float4*)(maskg + (size_t)b * S_ + tid * 4);
        *(float4*)&Em[tid * 4] = make_float4(mv.x * LOG2E, mv.y * LOG2E,
                                             mv.z * LOG2E, mv.w * LOG2E);
    }

    // ---- Q fragments: 32 q-rows = 2 x 16 (qh), scale folded in ----
    const int qrow0 = qt * BQ + wq * 32 + l15;
    bf16x8 qf[2][2];
#pragma unroll
    for (int qh = 0; qh < 2; ++qh) {
        const float* qp = qg + (size_t)(b * S_ + qrow0 + qh * 16) * ROWSZ + h * D_;
#pragma unroll
        for (int half = 0; half < 2; ++half) {
            float4 f0 = *(const float4*)(qp + half * 32 + g * 8);
            float4 f1 = *(const float4*)(qp + half * 32 + g * 8 + 4);
            union { bf16x8 v; uint4 u; } x;
            x.u = make_uint4(pack2(f0.x * SCALE2, f0.y * SCALE2),
                             pack2(f0.z * SCALE2, f0.w * SCALE2),
                             pack2(f1.x * SCALE2, f1.y * SCALE2),
                             pack2(f1.z * SCALE2, f1.w * SCALE2));
            qf[qh][half] = x.v;
        }
    }

    // ---- staging maps (identical to r9; all 512 threads stage full tile) ----
    const int skey = tid >> 4;
    const int sd   = (tid & 15) * 4;
    const int kw0 = (skey >> 4) * 1024
                  + ((sd >> 3) + ((skey >> 3) & 1) * 8) * 64
                  + (((skey & 7) ^ (sd >> 3)) << 3) + (sd & 7);
    const int kw1 = kw0 + 2048;
    const int vwA = ((w >> 1) * 4 + (lane >> 4)) * 256
                  + ((2 * w) & 3) * 64 + (lane & 15) * 4;
    const int vwB = vwA + 64;

    const size_t kvbase = (size_t)b * S_ * ROWSZ + h * D_;

    float4 kpre0, kpre1;
    float  vpre[8];
    auto prefetch = [&](int kt) {
        const float* kb = kg + kvbase + (size_t)kt * BK * ROWSZ;
        kpre0 = *(const float4*)(kb + (size_t)skey * ROWSZ + sd);
        kpre1 = *(const float4*)(kb + (size_t)(skey + 32) * ROWSZ + sd);
        const float* vb = vg + kvbase + (size_t)kt * BK * ROWSZ + lane;
#pragma unroll
        for (int i = 0; i < 8; ++i) vpre[i] = vb[(size_t)(w * 8 + i) * ROWSZ];
    };
    auto stage = [&](int buf) {
        *(uint2*)&Ks[buf * 4096 + kw0] =
            make_uint2(pack2(kpre0.x, kpre0.y), pack2(kpre0.z, kpre0.w));
        *(uint2*)&Ks[buf * 4096 + kw1] =
            make_uint2(pack2(kpre1.x, kpre1.y), pack2(kpre1.z, kpre1.w));
        *(uint2*)&Vt[buf * 4096 + vwA] =
            make_uint2(pack2(vpre[0], vpre[1]), pack2(vpre[2], vpre[3]));
        *(uint2*)&Vt[buf * 4096 + vwB] =
            make_uint2(pack2(vpre[4], vpre[5]), pack2(vpre[6], vpre[7]));
    };

    float l_r[2] = {0.0f, 0.0f};        // per-lane partial denom, per qh
    f32x4 o_acc[2][4];
#pragma unroll
    for (int qh = 0; qh < 2; ++qh)
#pragma unroll
        for (int t = 0; t < 4; ++t) o_acc[qh][t] = (f32x4){0.f, 0.f, 0.f, 0.f};

    prefetch(0);
    stage(0);
    __syncthreads();                    // also covers Em staging

    // ---- read bases (thread-constant) ----
    const int krd0 = (g + (l15 >> 3) * 8) * 64 + (((l15 & 7) ^ g) << 3);
    const int krd1 = (g + 4 + (l15 >> 3) * 8) * 64 + (((l15 & 7) ^ (g + 4)) << 3);
    const int vrd = g * 64 + l15 * 4;

    for (int kt = 0; kt < NT; ++kt) {
        const int cur = kt & 1;
        if (kt + 1 < NT) prefetch(kt + 1);

        // ---- QK + fused softmax on this wave's 2 K-subtiles x 2 q-halves ----
        const ushort* ks = Ks + cur * 4096;
        bf16x4 pf[2][2];                // [t_local][qh]
        float rs0 = 0.f, rs1 = 0.f;
#pragma unroll
        for (int t = 0; t < 2; ++t) {
            const int ts = 2 * wk + t;  // global 16-key subtile
            f32x4 e = *(const f32x4*)&Em[kt * BK + ts * 16 + g * 4];
            bf16x8 kf0 = *(const bf16x8*)&ks[ts * 1024 + krd0];
            bf16x8 kf1 = *(const bf16x8*)&ks[ts * 1024 + krd1];
#pragma unroll
            for (int qh = 0; qh < 2; ++qh) {
                f32x4 acc = e;
                acc = __builtin_amdgcn_mfma_f32_16x16x32_bf16(kf0, qf[qh][0], acc, 0, 0, 0);
                acc = __builtin_amdgcn_mfma_f32_16x16x32_bf16(kf1, qf[qh][1], acc, 0, 0, 0);
                float p0 = fexp2(acc[0]), p1 = fexp2(acc[1]);
                float p2 = fexp2(acc[2]), p3 = fexp2(acc[3]);
                if (qh == 0) rs0 += (p0 + p1) + (p2 + p3);
                else         rs1 += (p0 + p1) + (p2 + p3);
                union { bf16x4 v; uint2 u; } x;
                x.u = make_uint2(pack2(p0, p1), pack2(p2, p3));
                pf[t][qh] = x.v;
            }
        }
        l_r[0] += rs0;
        l_r[1] += rs1;

        // ---- O^T += V^T P^T : 8 b64 reads, each feeds 2 MFMA (q-reuse) ----
        const ushort* vt = Vt + cur * 4096;
#pragma unroll
        for (int c = 0; c < 2; ++c) {
            const int cs = 2 * wk + c;
#pragma unroll
            for (int t2 = 0; t2 < 4; ++t2) {
                bf16x4 vf = *(const bf16x4*)&vt[(cs * 4 + t2) * 256 + vrd];
                o_acc[0][t2] = mfma16(vf, pf[c][0], o_acc[0][t2]);
                o_acc[1][t2] = mfma16(vf, pf[c][1], o_acc[1][t2]);
            }
        }

        if (kt + 1 < NT) stage(cur ^ 1);
        __syncthreads();                // single barrier per tile
    }
    // loop ended with __syncthreads(): all LDS reads done -> overlay is safe

    // ---- combine key-halves (linear, fixed-base): waves wk=1 -> LDS ----
    f32x4* ovl = (f32x4*)Pool;          // [8][256] = 32KB
    float* lvl = Em;                    // reuse (mask no longer needed)
    if (wk == 1) {
#pragma unroll
        for (int qh = 0; qh < 2; ++qh) {
#pragma unroll
            for (int t2 = 0; t2 < 4; ++t2)
                ovl[(qh * 4 + t2) * 256 + wq * 64 + lane] = o_acc[qh][t2];
            lvl[qh * 256 + wq * 64 + lane] = l_r[qh];
        }
    }
    __syncthreads();
    if (wk == 0) {
#pragma unroll
        for (int qh = 0; qh < 2; ++qh) {
            l_r[qh] += lvl[qh * 256 + wq * 64 + lane];
#pragma unroll
            for (int t2 = 0; t2 < 4; ++t2) {
                f32x4 p = ovl[(qh * 4 + t2) * 256 + wq * 64 + lane];
                o_acc[qh][t2][0] += p[0]; o_acc[qh][t2][1] += p[1];
                o_acc[qh][t2][2] += p[2]; o_acc[qh][t2][3] += p[3];
            }
            float lr = l_r[qh];
            lr += __shfl_xor(lr, 16);
            lr += __shfl_xor(lr, 32);
            const float inv = 1.0f / lr;
            float* op = outg + (size_t)(b * S_ + qrow0 + qh * 16) * ROWSZ + h * D_;
#pragma unroll
            for (int t2 = 0; t2 < 4; ++t2)
#pragma unroll
                for (int r = 0; r < 4; ++r)
                    op[t2 * 16 + g * 4 + r] = o_acc[qh][t2][r] * inv;
        }
    }
}

extern "C" void kernel_launch(void* const* d_in, const int* in_sizes, int n_in,
                              void* d_out, int out_size, void* d_ws, size_t ws_size,
                              hipStream_t stream) {
    dim3 grid(S_ / BQ, H_, B_);   // (16,16,2) = 512 blocks, 2/CU
    fattn_kernel<<<grid, dim3(512), 0, stream>>>(
        (const float*)d_in[0], (const float*)d_in[1], (const float*)d_in[2],
        (const float*)d_in[3], (float*)d_out);
}